// Round 1
// baseline (4690.414 us; speedup 1.0000x reference)
//
#include <hip/hip_runtime.h>

// ---------------------------------------------------------------------------
// Cosine-similarity MHA, f32 baseline (round 1).
// b=1024, n_t=50, n_c=200, EMB=128, 8 heads x 32.
// Block = (batch, head), 512 threads, XCD-chunk swizzle so the 8 heads of a
// batch share one XCD's L2 (keys/values read from HBM once).
// Cross-head R-projection: out_h -> d_ws, second kernel; atomic fallback if
// ws_size < 52.4 MB.
// ---------------------------------------------------------------------------

#define NT 50
#define NC 200
#define EMB 128
#define DH 32
#define NH 8
#define THREADS 512

typedef float4 f4;

__device__ __forceinline__ float dot4(f4 a, f4 b) {
    return a.x * b.x + a.y * b.y + a.z * b.z + a.w * b.w;
}
__device__ __forceinline__ f4 axpy4(float a, f4 x, f4 y) {
    y.x += a * x.x; y.y += a * x.y; y.z += a * x.z; y.w += a * x.w; return y;
}

template <int WSP>
__global__ __launch_bounds__(THREADS) void attn_main(
    const float* __restrict__ gq, const float* __restrict__ gk,
    const float* __restrict__ gv,
    const float* __restrict__ At_w, const float* __restrict__ At_b,
    const float* __restrict__ Ac_w, const float* __restrict__ Ac_b,
    const float* __restrict__ Bc_w, const float* __restrict__ Bc_b,
    const float* __restrict__ pos_bias,
    const float* __restrict__ R_w, const float* __restrict__ R_b,
    float* __restrict__ out, float* __restrict__ att,
    float* __restrict__ ws, int nbat)
{
    const int t = threadIdx.x;
    const int p = blockIdx.x;
    const int chunk = (nbat * NH) >> 3;          // blocks per XCD
    const int lj = (p & 7) * chunk + (p >> 3);   // XCD-chunk swizzle
    const int b = lj >> 3;
    const int h = lj & 7;

    __shared__ float sW[32][132];   // weight slice, c-major, padded
    __shared__ float sK[NC][36];    // k_h, padded for score-phase f4 reads
    __shared__ float sV[NC][DH];    // v_h
    __shared__ float sQ[NT][36];    // q_h, padded
    __shared__ float sS[NT][204];   // scores / att, padded
    __shared__ float sO[NT][DH];    // out_h
    __shared__ float sqn[NT];
    __shared__ float skn[NC];
    __shared__ float spb[NC];

    if (t < NC) spb[t] = pos_bias[t];

    // ---- stage At slice: sW[c][i] = At_w[h*32+c][i] ----
    {
        const float* Wg = At_w + (size_t)(h * DH) * EMB;
        #pragma unroll
        for (int k = 0; k < 8; ++k) {
            int o = t + k * THREADS;             // o = c*128 + i
            sW[o >> 7][o & 127] = Wg[o];
        }
    }
    __syncthreads();

    // ---- q projection -> sQ ----
    {
        const int c = t & 31, rb = t >> 5;
        const float bias = At_b[h * DH + c];
        float acc[4];
        #pragma unroll
        for (int u = 0; u < 4; ++u) acc[u] = bias;
        const f4* qb = reinterpret_cast<const f4*>(gq + (size_t)b * NT * EMB);
        #pragma unroll
        for (int i4 = 0; i4 < 32; ++i4) {
            f4 w4 = *reinterpret_cast<const f4*>(&sW[c][i4 * 4]);
            #pragma unroll
            for (int u = 0; u < 4; ++u) {
                int r = rb + 16 * u; r = (r < NT) ? r : (NT - 1);
                acc[u] += dot4(w4, qb[r * 32 + i4]);
            }
        }
        #pragma unroll
        for (int u = 0; u < 4; ++u) {
            int r = rb + 16 * u;
            if (r < NT) sQ[r][c] = acc[u];
        }
    }
    __syncthreads();

    // q norms + stage Ac slice
    if (t < NT) {
        float s = 0.f;
        #pragma unroll
        for (int c = 0; c < DH; ++c) { float v = sQ[t][c]; s += v * v; }
        sqn[t] = sqrtf(s);
    }
    {
        const float* Wg = Ac_w + (size_t)(h * DH) * EMB;
        #pragma unroll
        for (int k = 0; k < 8; ++k) {
            int o = t + k * THREADS;
            sW[o >> 7][o & 127] = Wg[o];
        }
    }
    __syncthreads();

    // ---- k projection -> sK (stride 36) ----
    {
        const int c = t & 31, jb = t >> 5;
        const float bv = Ac_b[h * DH + c];
        float acc[13];
        #pragma unroll
        for (int u = 0; u < 13; ++u) acc[u] = bv;
        const f4* inb = reinterpret_cast<const f4*>(gk + (size_t)b * NC * EMB);
        #pragma unroll
        for (int i4 = 0; i4 < 32; ++i4) {
            f4 w4 = *reinterpret_cast<const f4*>(&sW[c][i4 * 4]);
            #pragma unroll
            for (int u = 0; u < 13; ++u) {
                int ju = jb + 16 * u; ju = (ju < NC) ? ju : (NC - 1);
                acc[u] += dot4(w4, inb[ju * 32 + i4]);
            }
        }
        #pragma unroll
        for (int u = 0; u < 13; ++u) {
            int ju = jb + 16 * u;
            if (ju < NC) sK[ju][c] = acc[u];
        }
    }
    __syncthreads();

    // k norms + stage Bc slice
    if (t < NC) {
        float s = 0.f;
        #pragma unroll
        for (int c = 0; c < DH; ++c) { float v = sK[t][c]; s += v * v; }
        skn[t] = sqrtf(s);
    }
    {
        const float* Wg = Bc_w + (size_t)(h * DH) * EMB;
        #pragma unroll
        for (int k = 0; k < 8; ++k) {
            int o = t + k * THREADS;
            sW[o >> 7][o & 127] = Wg[o];
        }
    }
    __syncthreads();

    // ---- v projection -> sV (stride 32) ----
    {
        const int c = t & 31, jb = t >> 5;
        const float bv = Bc_b[h * DH + c];
        float acc[13];
        #pragma unroll
        for (int u = 0; u < 13; ++u) acc[u] = bv;
        const f4* inb = reinterpret_cast<const f4*>(gv + (size_t)b * NC * EMB);
        #pragma unroll
        for (int i4 = 0; i4 < 32; ++i4) {
            f4 w4 = *reinterpret_cast<const f4*>(&sW[c][i4 * 4]);
            #pragma unroll
            for (int u = 0; u < 13; ++u) {
                int ju = jb + 16 * u; ju = (ju < NC) ? ju : (NC - 1);
                acc[u] += dot4(w4, inb[ju * 32 + i4]);
            }
        }
        #pragma unroll
        for (int u = 0; u < 13; ++u) {
            int ju = jb + 16 * u;
            if (ju < NC) sV[ju][c] = acc[u];
        }
    }

    // ---- scores: sS[r][j] = q.k/max(|q||k|,eps) + pb  (4 rows x 1 col tiles) ----
    for (int k = 0; k < 6; ++k) {
        int m = t + k * THREADS;
        if (m >= 13 * NC) break;                  // 13 row-quads * 200 cols
        int rq = m / NC, jj = m - rq * NC;
        int r0 = rq * 4;
        int r1 = (r0 + 1 < NT) ? r0 + 1 : NT - 1;
        int r2 = (r0 + 2 < NT) ? r0 + 2 : NT - 1;
        int r3 = (r0 + 3 < NT) ? r0 + 3 : NT - 1;
        float a0 = 0, a1 = 0, a2 = 0, a3 = 0;
        #pragma unroll
        for (int d4 = 0; d4 < 8; ++d4) {
            f4 kv = *reinterpret_cast<const f4*>(&sK[jj][d4 * 4]);
            a0 += dot4(*reinterpret_cast<const f4*>(&sQ[r0][d4 * 4]), kv);
            a1 += dot4(*reinterpret_cast<const f4*>(&sQ[r1][d4 * 4]), kv);
            a2 += dot4(*reinterpret_cast<const f4*>(&sQ[r2][d4 * 4]), kv);
            a3 += dot4(*reinterpret_cast<const f4*>(&sQ[r3][d4 * 4]), kv);
        }
        float knv = skn[jj], pbv = spb[jj];
        sS[r0][jj] = a0 / fmaxf(sqn[r0] * knv, 1e-6f) + pbv;
        if (r0 + 1 < NT) sS[r0 + 1][jj] = a1 / fmaxf(sqn[r0 + 1] * knv, 1e-6f) + pbv;
        if (r0 + 2 < NT) sS[r0 + 2][jj] = a2 / fmaxf(sqn[r0 + 2] * knv, 1e-6f) + pbv;
        if (r0 + 3 < NT) sS[r0 + 3][jj] = a3 / fmaxf(sqn[r0 + 3] * knv, 1e-6f) + pbv;
    }
    __syncthreads();

    // ---- softmax: 4 lanes per row ----
    if (t < NC) {
        int r = t >> 2, pq = t & 3;
        float mx = -1e30f;
        #pragma unroll 2
        for (int k = 0; k < NT; ++k) mx = fmaxf(mx, sS[r][pq + 4 * k]);
        mx = fmaxf(mx, __shfl_xor(mx, 1));
        mx = fmaxf(mx, __shfl_xor(mx, 2));
        float sum = 0.f;
        #pragma unroll 2
        for (int k = 0; k < NT; ++k) {
            float e = __expf(sS[r][pq + 4 * k] - mx);
            sS[r][pq + 4 * k] = e;
            sum += e;
        }
        sum += __shfl_xor(sum, 1);
        sum += __shfl_xor(sum, 2);
        float inv = 1.0f / sum;
        #pragma unroll 2
        for (int k = 0; k < NT; ++k) sS[r][pq + 4 * k] *= inv;
    }
    __syncthreads();

    // ---- att write (coalesced: o = r*200 + j is the global layout too) ----
    {
        float* attb = att + (size_t)(b * NH + h) * NT * NC;
        #pragma unroll
        for (int k = 0; k < 20; ++k) {
            int o = t + k * THREADS;
            if (o < NT * NC) {
                int r = o / NC;
                attb[o] = sS[r][o - r * NC];
            }
        }
    }

    // ---- PV: sO[r][c] = sum_j att[r][j] * v[j][c]  (unit = (r, c-quad)) ----
    if (t < NT * 8) {
        int r = t >> 3, cq = t & 7;
        f4 acc = {0.f, 0.f, 0.f, 0.f};
        #pragma unroll 2
        for (int jc = 0; jc < NC / 4; ++jc) {
            f4 s4 = *reinterpret_cast<const f4*>(&sS[r][jc * 4]);
            f4 v0 = *reinterpret_cast<const f4*>(&sV[jc * 4 + 0][cq * 4]);
            f4 v1 = *reinterpret_cast<const f4*>(&sV[jc * 4 + 1][cq * 4]);
            f4 v2 = *reinterpret_cast<const f4*>(&sV[jc * 4 + 2][cq * 4]);
            f4 v3 = *reinterpret_cast<const f4*>(&sV[jc * 4 + 3][cq * 4]);
            acc = axpy4(s4.x, v0, acc);
            acc = axpy4(s4.y, v1, acc);
            acc = axpy4(s4.z, v2, acc);
            acc = axpy4(s4.w, v3, acc);
        }
        *reinterpret_cast<f4*>(&sO[r][cq * 4]) = acc;
    }
    __syncthreads();

    if (WSP) {
        // ---- out_h -> workspace ----
        float* wsb = ws + (size_t)(b * NH + h) * NT * DH;
        #pragma unroll
        for (int k = 0; k < 4; ++k) {
            int o = t + k * THREADS;
            if (o < NT * DH) wsb[o] = sO[o >> 5][o & 31];
        }
    } else {
        // ---- atomic fallback: contrib = sO @ R_h^T, atomicAdd into out ----
        #pragma unroll
        for (int k = 0; k < 8; ++k) {
            int o = t + k * THREADS;             // 4096: c = o&31, e = o>>5
            int c = o & 31, e = o >> 5;
            sW[c][e] = R_w[(size_t)e * (NH * DH) + h * DH + c];
        }
        __syncthreads();
        for (int k = 0; k < 13; ++k) {
            int o = t + k * THREADS;
            if (o >= NT * EMB) break;
            int r = o >> 7, e = o & 127;
            float acc = (h == 0) ? R_b[e] : 0.f;
            #pragma unroll
            for (int c = 0; c < DH; ++c) acc += sO[r][c] * sW[c][e];
            atomicAdd(&out[((size_t)b * NT + r) * EMB + e], acc);
        }
    }
}

// out[b][r][e] = R_b[e] + sum_q ws[b][q/32][r][q%32] * R_w[e][q]
__global__ __launch_bounds__(256) void rproj(
    const float* __restrict__ ws, const float* __restrict__ R_w,
    const float* __restrict__ R_b, float* __restrict__ out)
{
    __shared__ float sR[NH * DH][129];           // sR[q][e] = R_w[e][q]
    const int b = blockIdx.x, t = threadIdx.x;
    #pragma unroll
    for (int k = 0; k < 128; ++k) {
        int o = t + k * 256;                     // 32768 = 128*256
        int q = o & 255, e = o >> 8;
        sR[q][e] = R_w[(size_t)e * 256 + q];
    }
    __syncthreads();

    const int e = t & 127, rg = t >> 7;          // rg in {0,1} -> 25 rows each
    const float* wsb = ws + (size_t)b * (NH * NT * DH);
    float acc[25];
    const float rb = R_b[e];
    #pragma unroll
    for (int k = 0; k < 25; ++k) acc[k] = rb;

    for (int q4 = 0; q4 < 64; ++q4) {
        int q0 = q4 * 4;
        float w0 = sR[q0][e], w1 = sR[q0 + 1][e];
        float w2 = sR[q0 + 2][e], w3 = sR[q0 + 3][e];
        int hh = q0 >> 5, c0 = q0 & 31;
        const f4* base = reinterpret_cast<const f4*>(wsb + (size_t)hh * NT * DH + c0);
        #pragma unroll
        for (int k = 0; k < 25; ++k) {
            int r = rg * 25 + k;
            f4 x = base[r * 8];                  // (hh*50 + r)*32 + c0, /4
            acc[k] += x.x * w0 + x.y * w1 + x.z * w2 + x.w * w3;
        }
    }
    #pragma unroll
    for (int k = 0; k < 25; ++k) {
        out[((size_t)b * NT + rg * 25 + k) * EMB + e] = acc[k];
    }
}

extern "C" void kernel_launch(void* const* d_in, const int* in_sizes, int n_in,
                              void* d_out, int out_size, void* d_ws, size_t ws_size,
                              hipStream_t stream)
{
    const float* gq   = (const float*)d_in[0];
    const float* gk   = (const float*)d_in[1];
    const float* gv   = (const float*)d_in[2];
    const float* At_w = (const float*)d_in[3];
    const float* At_b = (const float*)d_in[4];
    const float* Ac_w = (const float*)d_in[5];
    const float* Ac_b = (const float*)d_in[6];
    const float* Bc_w = (const float*)d_in[7];
    const float* Bc_b = (const float*)d_in[8];
    const float* pb   = (const float*)d_in[9];
    const float* R_w  = (const float*)d_in[10];
    const float* R_b  = (const float*)d_in[11];

    const int nbat = in_sizes[0] / (NT * EMB);   // 1024
    float* out = (float*)d_out;
    float* att = out + (size_t)nbat * NT * EMB;

    const size_t ws_need = (size_t)nbat * NH * NT * DH * sizeof(float);
    const int nwg = nbat * NH;

    if (ws_size >= ws_need) {
        attn_main<1><<<nwg, THREADS, 0, stream>>>(
            gq, gk, gv, At_w, At_b, Ac_w, Ac_b, Bc_w, Bc_b, pb, R_w, R_b,
            out, att, (float*)d_ws, nbat);
        rproj<<<nbat, 256, 0, stream>>>((float*)d_ws, R_w, R_b, out);
    } else {
        hipMemsetAsync(d_out, 0, (size_t)nbat * NT * EMB * sizeof(float), stream);
        attn_main<0><<<nwg, THREADS, 0, stream>>>(
            gq, gk, gv, At_w, At_b, Ac_w, Ac_b, Bc_w, Bc_b, pb, R_w, R_b,
            out, att, nullptr, nbat);
    }
}

// Round 2
// 1048.739 us; speedup vs baseline: 4.4724x; 4.4724x over previous
//
#include <hip/hip_runtime.h>

// ---------------------------------------------------------------------------
// Cosine-similarity MHA, MFMA version (round 2).
// b=1024, n_t=50, n_c=200, EMB=128, 8 heads x 32.
// Block = (batch, head), 512 threads (8 waves), 2 blocks/CU (77.8 KB LDS).
// Projections: split-bf16 MFMA (f32-quality). Scores/PV: plain bf16 MFMA.
// Softmax f32 in LDS; att bf16 aliased over the f32 score buffer.
// ---------------------------------------------------------------------------

#define NT 50
#define NC 200
#define EMB 128
#define DH 32
#define NH 8
#define THREADS 512

typedef __attribute__((ext_vector_type(4))) float f4acc;
typedef __attribute__((ext_vector_type(8))) short bh8;

__device__ __forceinline__ f4acc mfma_bf16(bh8 a, bh8 b, f4acc c) {
    return __builtin_amdgcn_mfma_f32_16x16x32_bf16(a, b, c, 0, 0, 0);
}

__device__ __forceinline__ unsigned short bf16rne(float x) {
    unsigned int u = __float_as_uint(x);
    u += 0x7FFFu + ((u >> 16) & 1u);
    return (unsigned short)(u >> 16);
}

// 8 consecutive f32 -> hi/lo bf16 fragments (truncation split; err ~2^-16)
__device__ __forceinline__ void split8(const float* __restrict__ p, bh8& hi, bh8& lo) {
    float4 x0 = *reinterpret_cast<const float4*>(p);
    float4 x1 = *reinterpret_cast<const float4*>(p + 4);
    float xs[8] = {x0.x, x0.y, x0.z, x0.w, x1.x, x1.y, x1.z, x1.w};
    #pragma unroll
    for (int e = 0; e < 8; ++e) {
        unsigned int u = __float_as_uint(xs[e]);
        hi[e] = (short)(u >> 16);
        float hf = __uint_as_float(u & 0xFFFF0000u);
        float lf = xs[e] - hf;
        lo[e] = (short)(__float_as_uint(lf) >> 16);
    }
}

// X[nrows][128] @ W[.][128]^T + b -> bf16 tile in LDS.
// TR=false: dst[row*stride+col] (rows < dstRows). TR=true: dst[col*stride+row].
template <bool TR>
__device__ __forceinline__ void proj_mfma(
    const float* __restrict__ X, int nrows,
    const float* __restrict__ W, const float* __restrict__ Wb,
    unsigned short* __restrict__ dst, int dstStride, int dstRows,
    int MT, int nTiles, int lane, int wave)
{
    const int l15 = lane & 15, g = lane >> 4;
    for (int id = wave; id < nTiles; id += 8) {
        const int mt = id % MT, nt = id / MT;
        const int m0 = mt << 4, n0 = nt << 4;
        int arow = m0 + l15; if (arow >= nrows) arow = nrows - 1;
        const float* ap = X + (size_t)arow * EMB + (g << 3);
        const float* bp = W + (size_t)(n0 + l15) * EMB + (g << 3);
        const float bias = Wb[n0 + l15];
        f4acc acc = {bias, bias, bias, bias};
        #pragma unroll
        for (int ks = 0; ks < 4; ++ks) {
            bh8 ah, al, bhv, blv;
            split8(ap + ks * 32, ah, al);
            split8(bp + ks * 32, bhv, blv);
            acc = mfma_bf16(ah, bhv, acc);
            acc = mfma_bf16(al, bhv, acc);
            acc = mfma_bf16(ah, blv, acc);
        }
        #pragma unroll
        for (int r = 0; r < 4; ++r) {
            const int row = m0 + (g << 2) + r;
            const unsigned short hb = bf16rne(acc[r]);
            if (TR) { if (row < nrows)   dst[(n0 + l15) * dstStride + row] = hb; }
            else    { if (row < dstRows) dst[row * dstStride + (n0 + l15)] = hb; }
        }
    }
}

template <int WSP>
__global__ __launch_bounds__(THREADS, 4) void attn_mfma(
    const float* __restrict__ gq, const float* __restrict__ gk,
    const float* __restrict__ gv,
    const float* __restrict__ At_w, const float* __restrict__ At_b,
    const float* __restrict__ Ac_w, const float* __restrict__ Ac_b,
    const float* __restrict__ Bc_w, const float* __restrict__ Bc_b,
    const float* __restrict__ pos_bias,
    const float* __restrict__ R_w, const float* __restrict__ R_b,
    float* __restrict__ out, float* __restrict__ att,
    float* __restrict__ ws, int nbat)
{
    const int t = threadIdx.x;
    const int p = blockIdx.x;
    const int chunk = (nbat * NH) >> 3;          // blocks per XCD (nwg%8==0)
    const int lj = (p & 7) * chunk + (p >> 3);   // XCD-chunk swizzle
    const int b = lj >> 3;
    const int h = lj & 7;
    const int lane = t & 63, wave = t >> 6;
    const int l15 = lane & 15, g = lane >> 4;

    __shared__ float          sS[NT * 204];      // 40800 B; bf16 att aliases it
    __shared__ unsigned short sK[NC * 40];       // 16000 B  k_h [200][32] pad 40
    __shared__ unsigned short sQ[64 * 40];       //  5120 B  q_h [64][32]  pad 40
    __shared__ unsigned short sVT[32 * 232];     // 14848 B  v_h^T [32][<=231]
    __shared__ float skn[NC];
    __shared__ float sqn[64];

    // zero sVT K-pad cols 200..231 (PV reads K up to 223; avoid NaN garbage)
    {
        const int c = t >> 4, kk = 200 + ((t & 15) << 1);
        *reinterpret_cast<unsigned int*>(&sVT[c * 232 + kk]) = 0u;
    }

    // ---- projections (split-bf16 MFMA) ----
    proj_mfma<false>(gq + (size_t)b * NT * EMB, NT,
                     At_w + (size_t)h * DH * EMB, At_b + h * DH,
                     sQ, 40, 64, 4, 8, lane, wave);
    proj_mfma<false>(gk + (size_t)b * NC * EMB, NC,
                     Ac_w + (size_t)h * DH * EMB, Ac_b + h * DH,
                     sK, 40, NC, 13, 26, lane, wave);
    proj_mfma<true>(gv + (size_t)b * NC * EMB, NC,
                    Bc_w + (size_t)h * DH * EMB, Bc_b + h * DH,
                    sVT, 232, NC, 13, 26, lane, wave);
    __syncthreads();

    // ---- norms from the bf16 values actually used in the dots ----
    if (t < NC) {
        const unsigned int* pr = reinterpret_cast<const unsigned int*>(&sK[t * 40]);
        float s = 0.f;
        #pragma unroll
        for (int i = 0; i < 16; ++i) {
            unsigned int v = pr[i];
            float a = __uint_as_float(v << 16);
            float c = __uint_as_float(v & 0xFFFF0000u);
            s += a * a + c * c;
        }
        skn[t] = sqrtf(s);
    } else if (t >= 256 && t < 320) {
        const int r = t - 256;
        const unsigned int* pr = reinterpret_cast<const unsigned int*>(&sQ[r * 40]);
        float s = 0.f;
        #pragma unroll
        for (int i = 0; i < 16; ++i) {
            unsigned int v = pr[i];
            float a = __uint_as_float(v << 16);
            float c = __uint_as_float(v & 0xFFFF0000u);
            s += a * a + c * c;
        }
        sqn[r] = sqrtf(s);
    }
    __syncthreads();

    // ---- scores: logits -> sS f32 (plain bf16 MFMA, K=32) ----
    {
        const int mt = wave & 3, m0 = mt << 4;
        const bh8 a = *reinterpret_cast<const bh8*>(&sQ[(m0 + l15) * 40 + (g << 3)]);
        for (int nt = wave >> 2; nt < 13; nt += 2) {
            const int n0 = nt << 4;
            const int col = n0 + l15;
            const int brow = (col < NC) ? col : (NC - 1);
            const bh8 bb = *reinterpret_cast<const bh8*>(&sK[brow * 40 + (g << 3)]);
            f4acc acc = {0.f, 0.f, 0.f, 0.f};
            acc = mfma_bf16(a, bb, acc);
            if (col < NC) {
                const float kn = skn[col];
                const float pb = pos_bias[col];
                #pragma unroll
                for (int r = 0; r < 4; ++r) {
                    const int row = m0 + (g << 2) + r;
                    if (row < NT)
                        sS[row * 204 + col] = acc[r] / fmaxf(sqn[row] * kn, 1e-6f) + pb;
                }
            }
        }
    }
    __syncthreads();

    // ---- softmax (8 lanes/row) + att f32 global write + bf16 sP (alias) ----
    unsigned short* sP = reinterpret_cast<unsigned short*>(sS);
    if (t < NT * 8) {
        const int r = t >> 3, pq = t & 7;
        float* row = sS + r * 204;
        float mx = -1e30f;
        #pragma unroll
        for (int k = 0; k < 25; ++k) mx = fmaxf(mx, row[pq + 8 * k]);
        mx = fmaxf(mx, __shfl_xor(mx, 1));
        mx = fmaxf(mx, __shfl_xor(mx, 2));
        mx = fmaxf(mx, __shfl_xor(mx, 4));
        float sum = 0.f;
        #pragma unroll
        for (int k = 0; k < 25; ++k) {
            float e = __expf(row[pq + 8 * k] - mx);
            row[pq + 8 * k] = e;
            sum += e;
        }
        sum += __shfl_xor(sum, 1);
        sum += __shfl_xor(sum, 2);
        sum += __shfl_xor(sum, 4);
        const float inv = 1.0f / sum;

        float vals[25];
        #pragma unroll
        for (int k = 0; k < 25; ++k) vals[k] = row[pq + 8 * k] * inv;
        asm volatile("" ::: "memory");           // f32 reads before bf16 alias writes

        float* attb = att + ((size_t)(b * NH + h) * NT + r) * NC;
        unsigned short* pr = sP + r * 408;       // row stride = 816 B = sS row
        #pragma unroll
        for (int k = 0; k < 25; ++k) {
            const int j = pq + 8 * k;
            attb[j] = vals[k];                   // byte 4j (trailing-safe)
            pr[j] = bf16rne(vals[k]);            // byte 2j
        }
        // zero K-pad cols 200..231 of this row (PV reads K up to 223)
        pr[200 + pq] = 0; pr[208 + pq] = 0; pr[216 + pq] = 0; pr[224 + pq] = 0;
    }
    __syncthreads();

    // ---- PV: out_h = att @ v  (plain bf16 MFMA, 7 K-steps) ----
    {
        const int mt = wave & 3, nt = wave >> 2;
        const int m0 = mt << 4, n0 = nt << 4;
        int arow = m0 + l15; if (arow >= NT) arow = NT - 1;
        const unsigned short* pA = sP + arow * 408 + (g << 3);
        const unsigned short* pB = sVT + (n0 + l15) * 232 + (g << 3);
        f4acc acc = {0.f, 0.f, 0.f, 0.f};
        #pragma unroll
        for (int ks = 0; ks < 7; ++ks) {
            const bh8 a = *reinterpret_cast<const bh8*>(pA + ks * 32);
            const bh8 v = *reinterpret_cast<const bh8*>(pB + ks * 32);
            acc = mfma_bf16(a, v, acc);
        }
        if (WSP) {
            float* wsb = ws + (size_t)(b * NH + h) * NT * DH;
            #pragma unroll
            for (int r = 0; r < 4; ++r) {
                const int row = m0 + (g << 2) + r;
                if (row < NT) wsb[row * DH + n0 + l15] = acc[r];
            }
        } else {
            __syncthreads();
            float* sOH = reinterpret_cast<float*>(sK);  // 6400 B <= 16000 B
            #pragma unroll
            for (int r = 0; r < 4; ++r) {
                const int row = m0 + (g << 2) + r;
                if (row < NT) sOH[row * DH + n0 + l15] = acc[r];
            }
        }
    }

    if (!WSP) {
        __syncthreads();
        const float* sOH = reinterpret_cast<const float*>(sK);
        for (int o = t; o < NT * EMB; o += THREADS) {
            const int r = o >> 7, e = o & 127;
            float s = (h == 0) ? R_b[e] : 0.f;
            const float* rw = R_w + (size_t)e * (NH * DH) + h * DH;
            const float* oh = sOH + r * DH;
            #pragma unroll
            for (int c = 0; c < DH; ++c) s += oh[c] * rw[c];
            atomicAdd(&out[((size_t)b * NT + r) * EMB + e], s);
        }
    }
}

// out[b][r][e] = R_b[e] + sum_q ws[b][q/32][r][q%32] * R_w[e][q]
__global__ __launch_bounds__(256) void rproj(
    const float* __restrict__ ws, const float* __restrict__ R_w,
    const float* __restrict__ R_b, float* __restrict__ out)
{
    __shared__ float sR[NH * DH][129];           // sR[q][e] = R_w[e][q]
    const int b = blockIdx.x, t = threadIdx.x;
    #pragma unroll
    for (int k = 0; k < 128; ++k) {
        int o = t + k * 256;                     // 32768 = 128*256
        int q = o & 255, e = o >> 8;
        sR[q][e] = R_w[(size_t)e * 256 + q];
    }
    __syncthreads();

    const int e = t & 127, rg = t >> 7;          // rg in {0,1} -> 25 rows each
    const float* wsb = ws + (size_t)b * (NH * NT * DH);
    float acc[25];
    const float rb = R_b[e];
    #pragma unroll
    for (int k = 0; k < 25; ++k) acc[k] = rb;

    for (int q4 = 0; q4 < 64; ++q4) {
        int q0 = q4 * 4;
        float w0 = sR[q0][e], w1 = sR[q0 + 1][e];
        float w2 = sR[q0 + 2][e], w3 = sR[q0 + 3][e];
        int hh = q0 >> 5, c0 = q0 & 31;
        const float4* base = reinterpret_cast<const float4*>(wsb + (size_t)hh * NT * DH + c0);
        #pragma unroll
        for (int k = 0; k < 25; ++k) {
            int r = rg * 25 + k;
            float4 x = base[r * 8];
            acc[k] += x.x * w0 + x.y * w1 + x.z * w2 + x.w * w3;
        }
    }
    #pragma unroll
    for (int k = 0; k < 25; ++k) {
        out[((size_t)b * NT + rg * 25 + k) * EMB + e] = acc[k];
    }
}

extern "C" void kernel_launch(void* const* d_in, const int* in_sizes, int n_in,
                              void* d_out, int out_size, void* d_ws, size_t ws_size,
                              hipStream_t stream)
{
    const float* gq   = (const float*)d_in[0];
    const float* gk   = (const float*)d_in[1];
    const float* gv   = (const float*)d_in[2];
    const float* At_w = (const float*)d_in[3];
    const float* At_b = (const float*)d_in[4];
    const float* Ac_w = (const float*)d_in[5];
    const float* Ac_b = (const float*)d_in[6];
    const float* Bc_w = (const float*)d_in[7];
    const float* Bc_b = (const float*)d_in[8];
    const float* pb   = (const float*)d_in[9];
    const float* R_w  = (const float*)d_in[10];
    const float* R_b  = (const float*)d_in[11];

    const int nbat = in_sizes[0] / (NT * EMB);   // 1024
    float* out = (float*)d_out;
    float* att = out + (size_t)nbat * NT * EMB;

    const size_t ws_need = (size_t)nbat * NH * NT * DH * sizeof(float);
    const int nwg = nbat * NH;

    if (ws_size >= ws_need) {
        attn_mfma<1><<<nwg, THREADS, 0, stream>>>(
            gq, gk, gv, At_w, At_b, Ac_w, Ac_b, Bc_w, Bc_b, pb, R_w, R_b,
            out, att, (float*)d_ws, nbat);
        rproj<<<nbat, 256, 0, stream>>>((float*)d_ws, R_w, R_b, out);
    } else {
        hipMemsetAsync(d_out, 0, (size_t)nbat * NT * EMB * sizeof(float), stream);
        attn_mfma<0><<<nwg, THREADS, 0, stream>>>(
            gq, gk, gv, At_w, At_b, Ac_w, Ac_b, Bc_w, Bc_b, pb, R_w, R_b,
            out, att, nullptr, nbat);
    }
}

// Round 4
// 836.937 us; speedup vs baseline: 5.6043x; 1.2531x over previous
//
#include <hip/hip_runtime.h>

// ---------------------------------------------------------------------------
// Cosine-similarity MHA, round 4: round-3 structure + fixed sP pad-zero
// (grid-stride loop; the `if (t<700)` with 512 threads left rows 37..49 of
// the K-pad as uninitialized LDS -> NaN*0 in PV).
// b=1024, n_t=50, n_c=200, EMB=128, 8 heads x 32. Block=(batch,head), 512 thr.
// ---------------------------------------------------------------------------

#define NT 50
#define NC 200
#define EMB 128
#define DH 32
#define NH 8
#define THREADS 512

typedef __attribute__((ext_vector_type(4))) float f4acc;
typedef __attribute__((ext_vector_type(8))) short bh8;

__device__ __forceinline__ f4acc mfma_bf16(bh8 a, bh8 b, f4acc c) {
    return __builtin_amdgcn_mfma_f32_16x16x32_bf16(a, b, c, 0, 0, 0);
}

__device__ __forceinline__ unsigned short bf16rne(float x) {
    unsigned int u = __float_as_uint(x);
    u += 0x7FFFu + ((u >> 16) & 1u);
    return (unsigned short)(u >> 16);
}

// 8 consecutive f32 -> hi/lo bf16 fragments (truncation split; err ~2^-16)
__device__ __forceinline__ void split8(const float* __restrict__ p, bh8& hi, bh8& lo) {
    float4 x0 = *reinterpret_cast<const float4*>(p);
    float4 x1 = *reinterpret_cast<const float4*>(p + 4);
    float xs[8] = {x0.x, x0.y, x0.z, x0.w, x1.x, x1.y, x1.z, x1.w};
    #pragma unroll
    for (int e = 0; e < 8; ++e) {
        unsigned int u = __float_as_uint(xs[e]);
        hi[e] = (short)(u >> 16);
        float hf = __uint_as_float(u & 0xFFFF0000u);
        float lf = xs[e] - hf;
        lo[e] = (short)(__float_as_uint(lf) >> 16);
    }
}

// LDS layout (byte offsets into smem[40928]):
//   sVT 0      : 32 x 232 shorts = 14848   v^T [col][k], 16B-aligned rows
//   sK  14848  : 200 x 40 shorts = 16000
//   sQ  30848  : 64 x 40 shorts  = 5120
//   sP  14848  : 50 x 232 shorts = 23200   (aliases sK+sQ after scores)
//   skn 38048  : 200 f32
//   sqn 38848  : 64 f32
//   spb 39104  : 200 f32
//   sM  39904  : 128 f32 (per-half row max)
//   sSm 40416  : 128 f32 (per-half row sum)

template <int WSP>
__global__ __launch_bounds__(THREADS, 6) void attn_mfma(
    const float* __restrict__ gq, const float* __restrict__ gk,
    const float* __restrict__ gv,
    const float* __restrict__ At_w, const float* __restrict__ At_b,
    const float* __restrict__ Ac_w, const float* __restrict__ Ac_b,
    const float* __restrict__ Bc_w, const float* __restrict__ Bc_b,
    const float* __restrict__ pos_bias,
    const float* __restrict__ R_w, const float* __restrict__ R_b,
    float* __restrict__ out, float* __restrict__ att,
    float* __restrict__ ws, int nbat)
{
    const int t = threadIdx.x;
    const int p = blockIdx.x;
    const int chunk = (nbat * NH) >> 3;
    const int lj = (p & 7) * chunk + (p >> 3);   // XCD-chunk swizzle (bijective)
    const int b = lj >> 3;
    const int h = lj & 7;
    const int lane = t & 63, wave = t >> 6;
    const int l15 = lane & 15, g = lane >> 4;

    __shared__ __align__(16) unsigned char smem[40928];
    unsigned short* sVT = reinterpret_cast<unsigned short*>(smem);
    unsigned short* sK  = reinterpret_cast<unsigned short*>(smem + 14848);
    unsigned short* sQ  = reinterpret_cast<unsigned short*>(smem + 30848);
    unsigned short* sP  = reinterpret_cast<unsigned short*>(smem + 14848);
    float* skn = reinterpret_cast<float*>(smem + 38048);
    float* sqn = reinterpret_cast<float*>(smem + 38848);
    float* spb = reinterpret_cast<float*>(smem + 39104);
    float* sM  = reinterpret_cast<float*>(smem + 39904);
    float* sSm = reinterpret_cast<float*>(smem + 40416);

    // ---- P0: zero sVT K-pad (k=200..227 for 32 cols), stage pos_bias ----
    if (t < 448) {
        unsigned int* v32 = reinterpret_cast<unsigned int*>(sVT);
        const int col = t / 14, i = t - col * 14;
        v32[col * 116 + 100 + i] = 0u;
    }
    if (t < NC) spb[t] = pos_bias[t];

    // ---- P1: projections, W-hoisted strips (split-bf16, 3-term) ----
    {
        const int s0 = (wave * 60) >> 3;
        const int s1 = ((wave + 1) * 60) >> 3;
        int cp = -1, cn = -1;
        bh8 wh[4], wl[4];
        float bias = 0.f;
        for (int id = s0; id < s1; ++id) {
            int pidx, nt, mt2;
            if (id < 8)       { pidx = 0; nt = id >> 2; mt2 = id & 3; }
            else if (id < 34) { int j = id - 8;  pidx = 1; nt = j / 13; mt2 = j - nt * 13; }
            else              { int j = id - 34; pidx = 2; nt = j / 13; mt2 = j - nt * 13; }
            const int col = (nt << 4) + l15;
            if (pidx != cp || nt != cn) {
                cp = pidx; cn = nt;
                const float* Wm = (pidx == 0) ? At_w : (pidx == 1) ? Ac_w : Bc_w;
                const float* Wb = (pidx == 0) ? At_b : (pidx == 1) ? Ac_b : Bc_b;
                const float* bp = Wm + (size_t)(h * DH + col) * EMB + (g << 3);
                #pragma unroll
                for (int ks = 0; ks < 4; ++ks) split8(bp + ks * 32, wh[ks], wl[ks]);
                bias = Wb[h * DH + col];
            }
            const int nrows = (pidx == 0) ? NT : NC;
            const float* Xb = (pidx == 0) ? gq : (pidx == 1) ? gk : gv;
            int ar = mt2 * 16 + l15; if (ar > nrows - 1) ar = nrows - 1;
            const float* ap = Xb + (size_t)b * nrows * EMB + (size_t)ar * EMB + (g << 3);
            f4acc acc2 = {bias, bias, bias, bias};
            #pragma unroll
            for (int ks = 0; ks < 4; ++ks) {
                bh8 xh, xl;
                split8(ap + ks * 32, xh, xl);
                acc2 = mfma_bf16(xh, wh[ks], acc2);
                acc2 = mfma_bf16(xl, wh[ks], acc2);
                acc2 = mfma_bf16(xh, wl[ks], acc2);
            }
            #pragma unroll
            for (int r = 0; r < 4; ++r) {
                const int row = mt2 * 16 + (g << 2) + r;
                if (row < nrows) {
                    const unsigned short hv = bf16rne(acc2[r]);
                    if (pidx == 0)      sQ[row * 40 + col] = hv;
                    else if (pidx == 1) sK[row * 40 + col] = hv;
                    else                sVT[col * 232 + row] = hv;
                }
            }
        }
    }
    __syncthreads();

    // ---- P2: norms from the bf16 values the MFMAs consume ----
    if (t < NC) {
        const uint4* pr = reinterpret_cast<const uint4*>(sK + t * 40);
        float s = 0.f;
        #pragma unroll
        for (int i = 0; i < 4; ++i) {
            uint4 u = pr[i];
            unsigned int w4[4] = {u.x, u.y, u.z, u.w};
            #pragma unroll
            for (int j = 0; j < 4; ++j) {
                float a = __uint_as_float(w4[j] << 16);
                float c = __uint_as_float(w4[j] & 0xFFFF0000u);
                s += a * a + c * c;
            }
        }
        skn[t] = sqrtf(s);
    } else if (t >= 256 && t < 320) {
        const int r = t - 256;
        float v = 1.0f;
        if (r < NT) {
            const uint4* pr = reinterpret_cast<const uint4*>(sQ + r * 40);
            float s = 0.f;
            #pragma unroll
            for (int i = 0; i < 4; ++i) {
                uint4 u = pr[i];
                unsigned int w4[4] = {u.x, u.y, u.z, u.w};
                #pragma unroll
                for (int j = 0; j < 4; ++j) {
                    float a = __uint_as_float(w4[j] << 16);
                    float c = __uint_as_float(w4[j] & 0xFFFF0000u);
                    s += a * a + c * c;
                }
            }
            v = sqrtf(s);
        }
        sqn[r] = v;
    }
    __syncthreads();

    // ---- P3: scores in registers (wave = m-tile (wave&3) x col-half (wave>>2)) ----
    const int mt = wave & 3, hf = wave >> 2;
    const int m0 = mt << 4;
    const int row64 = m0 + (g << 2);
    int arow = m0 + l15; if (arow > NT - 1) arow = NT - 1;
    const bh8 aq = *reinterpret_cast<const bh8*>(sQ + arow * 40 + (g << 3));
    float qn_r[4];
    #pragma unroll
    for (int r = 0; r < 4; ++r) qn_r[r] = sqn[row64 + r];

    f4acc acc[7];
    #pragma unroll
    for (int i = 0; i < 7; ++i) {
        const int nt = hf * 7 + i;
        if (nt < 13) {
            const int col = (nt << 4) + l15;
            const int bc = (col < NC) ? col : (NC - 1);
            const bh8 bk = *reinterpret_cast<const bh8*>(sK + bc * 40 + (g << 3));
            f4acc c = {0.f, 0.f, 0.f, 0.f};
            c = mfma_bf16(aq, bk, c);
            const float kn = skn[bc], pb = spb[bc];
            #pragma unroll
            for (int r = 0; r < 4; ++r)
                acc[i][r] = (col < NC) ? c[r] / fmaxf(qn_r[r] * kn, 1e-6f) + pb
                                       : -1e30f;
        }
    }
    __syncthreads();                 // sK/sQ dead; sP region live from here

    // ---- P4a: sP K-pad zero (ALL 50 rows; grid-stride!) + per-half row max ----
    {
        unsigned int* p32 = reinterpret_cast<unsigned int*>(sP);
        for (int tt = t; tt < 700; tt += THREADS) {
            const int row = tt / 14, i = tt - row * 14;
            p32[row * 116 + 100 + i] = 0u;
        }
    }
    {
        float mloc[4] = {-1e30f, -1e30f, -1e30f, -1e30f};
        #pragma unroll
        for (int i = 0; i < 7; ++i) {
            if (hf * 7 + i < 13) {
                #pragma unroll
                for (int r = 0; r < 4; ++r) mloc[r] = fmaxf(mloc[r], acc[i][r]);
            }
        }
        #pragma unroll
        for (int r = 0; r < 4; ++r) {
            mloc[r] = fmaxf(mloc[r], __shfl_xor(mloc[r], 1));
            mloc[r] = fmaxf(mloc[r], __shfl_xor(mloc[r], 2));
            mloc[r] = fmaxf(mloc[r], __shfl_xor(mloc[r], 4));
            mloc[r] = fmaxf(mloc[r], __shfl_xor(mloc[r], 8));
        }
        if (l15 == 0) {
            #pragma unroll
            for (int r = 0; r < 4; ++r) sM[hf * 64 + row64 + r] = mloc[r];
        }
    }
    __syncthreads();

    // ---- P4b: global max, exp, per-half sums ----
    {
        float mx[4], sl[4] = {0.f, 0.f, 0.f, 0.f};
        #pragma unroll
        for (int r = 0; r < 4; ++r)
            mx[r] = fmaxf(sM[row64 + r], sM[64 + row64 + r]);
        #pragma unroll
        for (int i = 0; i < 7; ++i) {
            if (hf * 7 + i < 13) {
                #pragma unroll
                for (int r = 0; r < 4; ++r) {
                    float e = __expf(acc[i][r] - mx[r]);
                    acc[i][r] = e;
                    sl[r] += e;
                }
            }
        }
        #pragma unroll
        for (int r = 0; r < 4; ++r) {
            sl[r] += __shfl_xor(sl[r], 1);
            sl[r] += __shfl_xor(sl[r], 2);
            sl[r] += __shfl_xor(sl[r], 4);
            sl[r] += __shfl_xor(sl[r], 8);
        }
        if (l15 == 0) {
            #pragma unroll
            for (int r = 0; r < 4; ++r) sSm[hf * 64 + row64 + r] = sl[r];
        }
    }
    __syncthreads();

    // ---- P4c: normalize, write att (f32 global) + P (bf16 LDS) ----
    {
        float inv[4];
        #pragma unroll
        for (int r = 0; r < 4; ++r)
            inv[r] = 1.0f / (sSm[row64 + r] + sSm[64 + row64 + r]);
        float* attb = att + (size_t)(b * NH + h) * NT * NC;
        #pragma unroll
        for (int i = 0; i < 7; ++i) {
            const int nt = hf * 7 + i;
            if (nt < 13) {
                const int col = (nt << 4) + l15;
                if (col < NC) {
                    #pragma unroll
                    for (int r = 0; r < 4; ++r) {
                        const int row = row64 + r;
                        if (row < NT) {
                            const float v = acc[i][r] * inv[r];
                            attb[row * NC + col] = v;
                            sP[row * 232 + col] = bf16rne(v);
                        }
                    }
                }
            }
        }
    }
    __syncthreads();

    // ---- P5: PV (bf16 MFMA, K=224 zero-padded) ----
    {
        const int pnt = wave >> 2;               // 2 col-tiles of 16 (DH=32)
        const unsigned short* pA = sP + arow * 232;
        const unsigned short* pB = sVT + (size_t)((pnt << 4) + l15) * 232;
        f4acc o = {0.f, 0.f, 0.f, 0.f};
        #pragma unroll
        for (int ks = 0; ks < 7; ++ks) {
            const bh8 a = *reinterpret_cast<const bh8*>(pA + ks * 32 + (g << 3));
            const bh8 v = *reinterpret_cast<const bh8*>(pB + ks * 32 + (g << 3));
            o = mfma_bf16(a, v, o);
        }
        if (WSP) {
            float* wsb = ws + (size_t)(b * NH + h) * NT * DH;
            #pragma unroll
            for (int r = 0; r < 4; ++r) {
                const int row = row64 + r;
                if (row < NT) wsb[row * DH + (pnt << 4) + l15] = o[r];
            }
        } else {
            __syncthreads();
            float* sOH = reinterpret_cast<float*>(smem);   // 6400 B over sVT
            #pragma unroll
            for (int r = 0; r < 4; ++r) {
                const int row = row64 + r;
                if (row < NT) sOH[row * DH + (pnt << 4) + l15] = o[r];
            }
            __syncthreads();
            for (int oo = t; oo < NT * EMB; oo += THREADS) {
                const int r = oo >> 7, e = oo & 127;
                float s = (h == 0) ? R_b[e] : 0.f;
                const float* rw = R_w + (size_t)e * (NH * DH) + h * DH;
                const float* oh = sOH + r * DH;
                #pragma unroll
                for (int c = 0; c < DH; ++c) s += oh[c] * rw[c];
                atomicAdd(&out[((size_t)b * NT + r) * EMB + e], s);
            }
        }
    }
}

// rproj v2: no LDS, grid = nbat*2, block 256. out[b][r][e] = R_b[e] + cat.R^T
__global__ __launch_bounds__(256) void rproj2(
    const float* __restrict__ ws, const float* __restrict__ R_w,
    const float* __restrict__ R_b, float* __restrict__ out)
{
    const int bidx = blockIdx.x;
    const int b = bidx >> 1, hlf = bidx & 1;
    const int t = threadIdx.x, e = t & 127, rh = t >> 7;
    const int r0 = hlf * 25 + rh * 13;
    const int nr = rh ? 12 : 13;
    const float* wsb = ws + (size_t)b * (NH * NT * DH);
    const float rb = R_b[e];
    float acc[13];
    #pragma unroll
    for (int i = 0; i < 13; ++i) acc[i] = rb;

    for (int q4 = 0; q4 < 64; ++q4) {
        const int q0 = q4 * 4, hh = q0 >> 5, c0 = q0 & 31;
        const float4 w = *reinterpret_cast<const float4*>(R_w + (size_t)e * 256 + q0);
        const float* xb = wsb + (size_t)hh * NT * DH + c0;
        #pragma unroll
        for (int i = 0; i < 13; ++i) {
            if (i < nr) {
                const float4 x = *reinterpret_cast<const float4*>(xb + (r0 + i) * DH);
                acc[i] += x.x * w.x + x.y * w.y + x.z * w.z + x.w * w.w;
            }
        }
    }
    #pragma unroll
    for (int i = 0; i < 13; ++i)
        if (i < nr) out[((size_t)b * NT + r0 + i) * EMB + e] = acc[i];
}

extern "C" void kernel_launch(void* const* d_in, const int* in_sizes, int n_in,
                              void* d_out, int out_size, void* d_ws, size_t ws_size,
                              hipStream_t stream)
{
    const float* gq   = (const float*)d_in[0];
    const float* gk   = (const float*)d_in[1];
    const float* gv   = (const float*)d_in[2];
    const float* At_w = (const float*)d_in[3];
    const float* At_b = (const float*)d_in[4];
    const float* Ac_w = (const float*)d_in[5];
    const float* Ac_b = (const float*)d_in[6];
    const float* Bc_w = (const float*)d_in[7];
    const float* Bc_b = (const float*)d_in[8];
    const float* pb   = (const float*)d_in[9];
    const float* R_w  = (const float*)d_in[10];
    const float* R_b  = (const float*)d_in[11];

    const int nbat = in_sizes[0] / (NT * EMB);   // 1024
    float* out = (float*)d_out;
    float* att = out + (size_t)nbat * NT * EMB;

    const size_t ws_need = (size_t)nbat * NH * NT * DH * sizeof(float);
    const int nwg = nbat * NH;

    if (ws_size >= ws_need) {
        attn_mfma<1><<<nwg, THREADS, 0, stream>>>(
            gq, gk, gv, At_w, At_b, Ac_w, Ac_b, Bc_w, Bc_b, pb, R_w, R_b,
            out, att, (float*)d_ws, nbat);
        rproj2<<<nbat * 2, 256, 0, stream>>>((float*)d_ws, R_w, R_b, out);
    } else {
        hipMemsetAsync(d_out, 0, (size_t)nbat * NT * EMB * sizeof(float), stream);
        attn_mfma<0><<<nwg, THREADS, 0, stream>>>(
            gq, gk, gv, At_w, At_b, Ac_w, Ac_b, Bc_w, Bc_b, pb, R_w, R_b,
            out, att, nullptr, nbat);
    }
}

// Round 5
// 790.496 us; speedup vs baseline: 5.9335x; 1.0587x over previous
//
#include <hip/hip_runtime.h>

// ---------------------------------------------------------------------------
// Cosine-similarity MHA, round 5:
//  - split8 via v_cvt_pk_bf16_f32 (pre-packed hi/lo, ~2x fewer VALU ops)
//  - P2 norm phase removed: norms in-register via shfl from MFMA fragments
//  - rproj3: no-LDS, s_load-uniform ws + per-thread R_w rows (L2-resident)
// b=1024, n_t=50, n_c=200, EMB=128, 8 heads x 32. Block=(batch,head), 512 thr.
// ---------------------------------------------------------------------------

#define NT 50
#define NC 200
#define EMB 128
#define DH 32
#define NH 8
#define THREADS 512

typedef __attribute__((ext_vector_type(4))) float f4acc;
typedef __attribute__((ext_vector_type(8))) short bh8;

__device__ __forceinline__ f4acc mfma_bf16(bh8 a, bh8 b, f4acc c) {
    return __builtin_amdgcn_mfma_f32_16x16x32_bf16(a, b, c, 0, 0, 0);
}

__device__ __forceinline__ unsigned short bf16rne(float x) {
    unsigned int u = __float_as_uint(x);
    u += 0x7FFFu + ((u >> 16) & 1u);
    return (unsigned short)(u >> 16);
}

// 8 consecutive f32 -> packed hi/lo bf16 fragments.
// hi = RNE(x) via v_cvt_pk_bf16_f32 (packs 2 f32 -> 1 dword of 2 bf16),
// lo = RNE(x - (float)hi). Any within-word pair order is applied identically
// to A and B fragments, so MFMA dot products are invariant to it.
__device__ __forceinline__ void split8(const float* __restrict__ p, bh8& hi, bh8& lo) {
    float4 x0 = *reinterpret_cast<const float4*>(p);
    float4 x1 = *reinterpret_cast<const float4*>(p + 4);
    float xs[8] = {x0.x, x0.y, x0.z, x0.w, x1.x, x1.y, x1.z, x1.w};
    union { unsigned int w[4]; bh8 v; } H, L;
    #pragma unroll
    for (int i = 0; i < 4; ++i) {
        const float a = xs[2 * i], b = xs[2 * i + 1];
        unsigned int hw, lw;
        asm("v_cvt_pk_bf16_f32 %0, %1, %2" : "=v"(hw) : "v"(a), "v"(b));
        const float ha = __uint_as_float(hw << 16);
        const float hb = __uint_as_float(hw & 0xFFFF0000u);
        const float la = a - ha, lb = b - hb;
        asm("v_cvt_pk_bf16_f32 %0, %1, %2" : "=v"(lw) : "v"(la), "v"(lb));
        H.w[i] = hw; L.w[i] = lw;
    }
    hi = H.v; lo = L.v;
}

// LDS layout (byte offsets into smem[39872]):
//   sVT 0      : 32 x 232 shorts = 14848   v^T [col][k]
//   sK  14848  : 200 x 40 shorts = 16000
//   sQ  30848  : 64 x 40 shorts  = 5120    (ends 35968)
//   sP  14848  : 50 x 232 shorts = 23200   (aliases sK+sQ, ends 38048)
//   spb 38048  : 200 f32
//   sM  38848  : 128 f32 (per-half row max)
//   sSm 39360  : 128 f32 (per-half row sum)

template <int WSP>
__global__ __launch_bounds__(THREADS, 6) void attn_mfma(
    const float* __restrict__ gq, const float* __restrict__ gk,
    const float* __restrict__ gv,
    const float* __restrict__ At_w, const float* __restrict__ At_b,
    const float* __restrict__ Ac_w, const float* __restrict__ Ac_b,
    const float* __restrict__ Bc_w, const float* __restrict__ Bc_b,
    const float* __restrict__ pos_bias,
    const float* __restrict__ R_w, const float* __restrict__ R_b,
    float* __restrict__ out, float* __restrict__ att,
    float* __restrict__ ws, int nbat)
{
    const int t = threadIdx.x;
    const int p = blockIdx.x;
    const int chunk = (nbat * NH) >> 3;
    const int lj = (p & 7) * chunk + (p >> 3);   // XCD-chunk swizzle (bijective)
    const int b = lj >> 3;
    const int h = lj & 7;
    const int lane = t & 63, wave = t >> 6;
    const int l15 = lane & 15, g = lane >> 4;

    __shared__ __align__(16) unsigned char smem[39872];
    unsigned short* sVT = reinterpret_cast<unsigned short*>(smem);
    unsigned short* sK  = reinterpret_cast<unsigned short*>(smem + 14848);
    unsigned short* sQ  = reinterpret_cast<unsigned short*>(smem + 30848);
    unsigned short* sP  = reinterpret_cast<unsigned short*>(smem + 14848);
    float* spb = reinterpret_cast<float*>(smem + 38048);
    float* sM  = reinterpret_cast<float*>(smem + 38848);
    float* sSm = reinterpret_cast<float*>(smem + 39360);

    // ---- P0: zero sVT K-pad (k=200..227 for 32 cols), stage pos_bias ----
    if (t < 448) {
        unsigned int* v32 = reinterpret_cast<unsigned int*>(sVT);
        const int col = t / 14, i = t - col * 14;
        v32[col * 116 + 100 + i] = 0u;
    }
    if (t < NC) spb[t] = pos_bias[t];

    // ---- P1: projections, W-hoisted strips (split-bf16, 3-term) ----
    {
        const int s0 = (wave * 60) >> 3;
        const int s1 = ((wave + 1) * 60) >> 3;
        int cp = -1, cn = -1;
        bh8 wh[4], wl[4];
        float bias = 0.f;
        for (int id = s0; id < s1; ++id) {
            int pidx, nt, mt2;
            if (id < 8)       { pidx = 0; nt = id >> 2; mt2 = id & 3; }
            else if (id < 34) { int j = id - 8;  pidx = 1; nt = j / 13; mt2 = j - nt * 13; }
            else              { int j = id - 34; pidx = 2; nt = j / 13; mt2 = j - nt * 13; }
            const int col = (nt << 4) + l15;
            if (pidx != cp || nt != cn) {
                cp = pidx; cn = nt;
                const float* Wm = (pidx == 0) ? At_w : (pidx == 1) ? Ac_w : Bc_w;
                const float* Wb = (pidx == 0) ? At_b : (pidx == 1) ? Ac_b : Bc_b;
                const float* bp = Wm + (size_t)(h * DH + col) * EMB + (g << 3);
                #pragma unroll
                for (int ks = 0; ks < 4; ++ks) split8(bp + ks * 32, wh[ks], wl[ks]);
                bias = Wb[h * DH + col];
            }
            const int nrows = (pidx == 0) ? NT : NC;
            const float* Xb = (pidx == 0) ? gq : (pidx == 1) ? gk : gv;
            int ar = mt2 * 16 + l15; if (ar > nrows - 1) ar = nrows - 1;
            const float* ap = Xb + (size_t)b * nrows * EMB + (size_t)ar * EMB + (g << 3);
            f4acc acc2 = {bias, bias, bias, bias};
            #pragma unroll
            for (int ks = 0; ks < 4; ++ks) {
                bh8 xh, xl;
                split8(ap + ks * 32, xh, xl);
                acc2 = mfma_bf16(xh, wh[ks], acc2);
                acc2 = mfma_bf16(xl, wh[ks], acc2);
                acc2 = mfma_bf16(xh, wl[ks], acc2);
            }
            #pragma unroll
            for (int r = 0; r < 4; ++r) {
                const int row = mt2 * 16 + (g << 2) + r;
                if (row < nrows) {
                    const unsigned short hv = bf16rne(acc2[r]);
                    if (pidx == 0)      sQ[row * 40 + col] = hv;
                    else if (pidx == 1) sK[row * 40 + col] = hv;
                    else                sVT[col * 232 + row] = hv;
                }
            }
        }
    }
    __syncthreads();

    // ---- P3: scores in registers; norms in-register from the fragments ----
    const int mt = wave & 3, hf = wave >> 2;
    const int m0 = mt << 4;
    const int row64 = m0 + (g << 2);
    int arow = m0 + l15; if (arow > NT - 1) arow = NT - 1;
    const bh8 aq = *reinterpret_cast<const bh8*>(sQ + arow * 40 + (g << 3));

    // qn: A-frag row m0+l15 lives on the 4 lanes {l15, l15+16, +32, +48}
    float qn2 = 0.f;
    #pragma unroll
    for (int e = 0; e < 8; ++e) {
        const float v = __uint_as_float(((unsigned int)(unsigned short)aq[e]) << 16);
        qn2 += v * v;
    }
    qn2 += __shfl_xor(qn2, 16);
    qn2 += __shfl_xor(qn2, 32);
    float qn_r[4];                       // move qn to this lane's 4 C-rows
    #pragma unroll
    for (int r = 0; r < 4; ++r) qn_r[r] = sqrtf(__shfl(qn2, (g << 2) + r, 64));

    f4acc acc[7];
    #pragma unroll
    for (int i = 0; i < 7; ++i) {
        const int nt = hf * 7 + i;
        if (nt < 13) {
            const int col = (nt << 4) + l15;
            const int bc = (col < NC) ? col : (NC - 1);
            const bh8 bk = *reinterpret_cast<const bh8*>(sK + bc * 40 + (g << 3));
            float kn2 = 0.f;
            #pragma unroll
            for (int e = 0; e < 8; ++e) {
                const float v = __uint_as_float(((unsigned int)(unsigned short)bk[e]) << 16);
                kn2 += v * v;
            }
            kn2 += __shfl_xor(kn2, 16);  // kn lands on C-col lanes directly
            kn2 += __shfl_xor(kn2, 32);
            const float kn = sqrtf(kn2);
            f4acc c = {0.f, 0.f, 0.f, 0.f};
            c = mfma_bf16(aq, bk, c);
            const float pb = spb[bc];
            #pragma unroll
            for (int r = 0; r < 4; ++r)
                acc[i][r] = (col < NC) ? c[r] / fmaxf(qn_r[r] * kn, 1e-6f) + pb
                                       : -1e30f;
        }
    }
    __syncthreads();                 // sK/sQ dead; sP region live from here

    // ---- P4a: sP K-pad zero (ALL 50 rows; grid-stride) + per-half row max ----
    {
        unsigned int* p32 = reinterpret_cast<unsigned int*>(sP);
        for (int tt = t; tt < 700; tt += THREADS) {
            const int row = tt / 14, i = tt - row * 14;
            p32[row * 116 + 100 + i] = 0u;
        }
    }
    {
        float mloc[4] = {-1e30f, -1e30f, -1e30f, -1e30f};
        #pragma unroll
        for (int i = 0; i < 7; ++i) {
            if (hf * 7 + i < 13) {
                #pragma unroll
                for (int r = 0; r < 4; ++r) mloc[r] = fmaxf(mloc[r], acc[i][r]);
            }
        }
        #pragma unroll
        for (int r = 0; r < 4; ++r) {
            mloc[r] = fmaxf(mloc[r], __shfl_xor(mloc[r], 1));
            mloc[r] = fmaxf(mloc[r], __shfl_xor(mloc[r], 2));
            mloc[r] = fmaxf(mloc[r], __shfl_xor(mloc[r], 4));
            mloc[r] = fmaxf(mloc[r], __shfl_xor(mloc[r], 8));
        }
        if (l15 == 0) {
            #pragma unroll
            for (int r = 0; r < 4; ++r) sM[hf * 64 + row64 + r] = mloc[r];
        }
    }
    __syncthreads();

    // ---- P4b: global max, exp, per-half sums ----
    {
        float mx[4], sl[4] = {0.f, 0.f, 0.f, 0.f};
        #pragma unroll
        for (int r = 0; r < 4; ++r)
            mx[r] = fmaxf(sM[row64 + r], sM[64 + row64 + r]);
        #pragma unroll
        for (int i = 0; i < 7; ++i) {
            if (hf * 7 + i < 13) {
                #pragma unroll
                for (int r = 0; r < 4; ++r) {
                    float e = __expf(acc[i][r] - mx[r]);
                    acc[i][r] = e;
                    sl[r] += e;
                }
            }
        }
        #pragma unroll
        for (int r = 0; r < 4; ++r) {
            sl[r] += __shfl_xor(sl[r], 1);
            sl[r] += __shfl_xor(sl[r], 2);
            sl[r] += __shfl_xor(sl[r], 4);
            sl[r] += __shfl_xor(sl[r], 8);
        }
        if (l15 == 0) {
            #pragma unroll
            for (int r = 0; r < 4; ++r) sSm[hf * 64 + row64 + r] = sl[r];
        }
    }
    __syncthreads();

    // ---- P4c: normalize, write att (f32 global) + P (bf16 LDS) ----
    {
        float inv[4];
        #pragma unroll
        for (int r = 0; r < 4; ++r)
            inv[r] = 1.0f / (sSm[row64 + r] + sSm[64 + row64 + r]);
        float* attb = att + (size_t)(b * NH + h) * NT * NC;
        #pragma unroll
        for (int i = 0; i < 7; ++i) {
            const int nt = hf * 7 + i;
            if (nt < 13) {
                const int col = (nt << 4) + l15;
                if (col < NC) {
                    #pragma unroll
                    for (int r = 0; r < 4; ++r) {
                        const int row = row64 + r;
                        if (row < NT) {
                            const float v = acc[i][r] * inv[r];
                            attb[row * NC + col] = v;
                            sP[row * 232 + col] = bf16rne(v);
                        }
                    }
                }
            }
        }
    }
    __syncthreads();

    // ---- P5: PV (bf16 MFMA, K=224 zero-padded) ----
    {
        const int pnt = wave >> 2;               // 2 col-tiles of 16 (DH=32)
        const unsigned short* pA = sP + arow * 232;
        const unsigned short* pB = sVT + (size_t)((pnt << 4) + l15) * 232;
        f4acc o = {0.f, 0.f, 0.f, 0.f};
        #pragma unroll
        for (int ks = 0; ks < 7; ++ks) {
            const bh8 a = *reinterpret_cast<const bh8*>(pA + ks * 32 + (g << 3));
            const bh8 v = *reinterpret_cast<const bh8*>(pB + ks * 32 + (g << 3));
            o = mfma_bf16(a, v, o);
        }
        if (WSP) {
            float* wsb = ws + (size_t)(b * NH + h) * NT * DH;
            #pragma unroll
            for (int r = 0; r < 4; ++r) {
                const int row = row64 + r;
                if (row < NT) wsb[row * DH + (pnt << 4) + l15] = o[r];
            }
        } else {
            __syncthreads();
            float* sOH = reinterpret_cast<float*>(smem);   // 6400 B over sVT
            #pragma unroll
            for (int r = 0; r < 4; ++r) {
                const int row = row64 + r;
                if (row < NT) sOH[row * DH + (pnt << 4) + l15] = o[r];
            }
            __syncthreads();
            for (int oo = t; oo < NT * EMB; oo += THREADS) {
                const int r = oo >> 7, e = oo & 127;
                float s = (h == 0) ? R_b[e] : 0.f;
                const float* rw = R_w + (size_t)e * (NH * DH) + h * DH;
                const float* oh = sOH + r * DH;
                #pragma unroll
                for (int c = 0; c < DH; ++c) s += oh[c] * rw[c];
                atomicAdd(&out[((size_t)b * NT + r) * EMB + e], s);
            }
        }
    }
}

// rproj3: no LDS. grid = nbat*2, block 256 (4 waves).
// Thread owns column e and 12-13 rows; R_w row per-thread (L2-resident
// vector loads); ws addresses wave-uniform (readfirstlane) -> s_load/SGPR.
__global__ __launch_bounds__(256) void rproj3(
    const float* __restrict__ ws, const float* __restrict__ R_w,
    const float* __restrict__ R_b, float* __restrict__ out)
{
    const int bidx = blockIdx.x;
    const int b = bidx >> 1, hlf = bidx & 1;
    const int t = threadIdx.x;
    const int lane = t & 63;
    const int wg    = __builtin_amdgcn_readfirstlane(t >> 7);          // 0/1
    const int ehalf = __builtin_amdgcn_readfirstlane((t >> 6) & 1);    // 0/1
    const int e = ehalf * 64 + lane;
    const int r0 = hlf * 25 + wg * 13;
    const int nr = wg ? 12 : 13;
    const float* wsb = ws + (size_t)b * (NH * NT * DH);
    const float* rw = R_w + (size_t)e * (NH * DH);
    const float rb = R_b[e];
    float acc[13];
    #pragma unroll
    for (int i = 0; i < 13; ++i) acc[i] = rb;

    for (int k0 = 0; k0 < NH * DH; k0 += 4) {
        const float4 w = *reinterpret_cast<const float4*>(rw + k0);
        const int hh = k0 >> 5, c0 = k0 & 31;
        const float* xrow = wsb + hh * (NT * DH) + c0;   // wave-uniform
        #pragma unroll
        for (int i = 0; i < 13; ++i) {
            if (i < nr) {
                const float4 x = *reinterpret_cast<const float4*>(xrow + (r0 + i) * DH);
                acc[i] += x.x * w.x + x.y * w.y + x.z * w.z + x.w * w.w;
            }
        }
    }
    #pragma unroll
    for (int i = 0; i < 13; ++i)
        if (i < nr) out[((size_t)b * NT + r0 + i) * EMB + e] = acc[i];
}

extern "C" void kernel_launch(void* const* d_in, const int* in_sizes, int n_in,
                              void* d_out, int out_size, void* d_ws, size_t ws_size,
                              hipStream_t stream)
{
    const float* gq   = (const float*)d_in[0];
    const float* gk   = (const float*)d_in[1];
    const float* gv   = (const float*)d_in[2];
    const float* At_w = (const float*)d_in[3];
    const float* At_b = (const float*)d_in[4];
    const float* Ac_w = (const float*)d_in[5];
    const float* Ac_b = (const float*)d_in[6];
    const float* Bc_w = (const float*)d_in[7];
    const float* Bc_b = (const float*)d_in[8];
    const float* pb   = (const float*)d_in[9];
    const float* R_w  = (const float*)d_in[10];
    const float* R_b  = (const float*)d_in[11];

    const int nbat = in_sizes[0] / (NT * EMB);   // 1024
    float* out = (float*)d_out;
    float* att = out + (size_t)nbat * NT * EMB;

    const size_t ws_need = (size_t)nbat * NH * NT * DH * sizeof(float);
    const int nwg = nbat * NH;

    if (ws_size >= ws_need) {
        attn_mfma<1><<<nwg, THREADS, 0, stream>>>(
            gq, gk, gv, At_w, At_b, Ac_w, Ac_b, Bc_w, Bc_b, pb, R_w, R_b,
            out, att, (float*)d_ws, nbat);
        rproj3<<<nbat * 2, 256, 0, stream>>>((float*)d_ws, R_w, R_b, out);
    } else {
        hipMemsetAsync(d_out, 0, (size_t)nbat * NT * EMB * sizeof(float), stream);
        attn_mfma<0><<<nwg, THREADS, 0, stream>>>(
            gq, gk, gv, At_w, At_b, Ac_w, Ac_b, Bc_w, Bc_b, pb, R_w, R_b,
            out, att, nullptr, nbat);
    }
}

// Round 6
// 621.082 us; speedup vs baseline: 7.5520x; 1.2728x over previous
//
#include <hip/hip_runtime.h>

// ---------------------------------------------------------------------------
// Cosine-similarity MHA, round 6:
//  - attn: __launch_bounds__(512,4) (128-VGPR budget; test of the
//    spill/AGPR-shuffle theory for the 6000-instr VALU anomaly)
//  - ws relayout to [b][r][h][c] (= cat rows) for MFMA rproj
//  - rproj4: split-bf16 MFMA GEMM  out = cat @ R_w^T + R_b
// b=1024, n_t=50, n_c=200, EMB=128, 8 heads x 32. Block=(batch,head), 512 thr.
// ---------------------------------------------------------------------------

#define NT 50
#define NC 200
#define EMB 128
#define DH 32
#define NH 8
#define THREADS 512

typedef __attribute__((ext_vector_type(4))) float f4acc;
typedef __attribute__((ext_vector_type(8))) short bh8;

__device__ __forceinline__ f4acc mfma_bf16(bh8 a, bh8 b, f4acc c) {
    return __builtin_amdgcn_mfma_f32_16x16x32_bf16(a, b, c, 0, 0, 0);
}

__device__ __forceinline__ unsigned short bf16rne(float x) {
    unsigned int u = __float_as_uint(x);
    u += 0x7FFFu + ((u >> 16) & 1u);
    return (unsigned short)(u >> 16);
}

// 8 consecutive f32 -> packed hi/lo bf16 fragments.
// hi = RNE(x) via v_cvt_pk_bf16_f32, lo = RNE(x - (float)hi). Pair order is
// applied identically to A and B fragments -> MFMA dots invariant.
__device__ __forceinline__ void split8(const float* __restrict__ p, bh8& hi, bh8& lo) {
    float4 x0 = *reinterpret_cast<const float4*>(p);
    float4 x1 = *reinterpret_cast<const float4*>(p + 4);
    float xs[8] = {x0.x, x0.y, x0.z, x0.w, x1.x, x1.y, x1.z, x1.w};
    union { unsigned int w[4]; bh8 v; } H, L;
    #pragma unroll
    for (int i = 0; i < 4; ++i) {
        const float a = xs[2 * i], b = xs[2 * i + 1];
        unsigned int hw, lw;
        asm("v_cvt_pk_bf16_f32 %0, %1, %2" : "=v"(hw) : "v"(a), "v"(b));
        const float ha = __uint_as_float(hw << 16);
        const float hb = __uint_as_float(hw & 0xFFFF0000u);
        const float la = a - ha, lb = b - hb;
        asm("v_cvt_pk_bf16_f32 %0, %1, %2" : "=v"(lw) : "v"(la), "v"(lb));
        H.w[i] = hw; L.w[i] = lw;
    }
    hi = H.v; lo = L.v;
}

// LDS layout (byte offsets into smem[39872]):
//   sVT 0      : 32 x 232 shorts = 14848   v^T [col][k]
//   sK  14848  : 200 x 40 shorts = 16000
//   sQ  30848  : 64 x 40 shorts  = 5120    (ends 35968)
//   sP  14848  : 50 x 232 shorts = 23200   (aliases sK+sQ, ends 38048)
//   spb 38048  : 200 f32
//   sM  38848  : 128 f32 (per-half row max)
//   sSm 39360  : 128 f32 (per-half row sum)

template <int WSP>
__global__ __launch_bounds__(THREADS, 4) void attn_mfma(
    const float* __restrict__ gq, const float* __restrict__ gk,
    const float* __restrict__ gv,
    const float* __restrict__ At_w, const float* __restrict__ At_b,
    const float* __restrict__ Ac_w, const float* __restrict__ Ac_b,
    const float* __restrict__ Bc_w, const float* __restrict__ Bc_b,
    const float* __restrict__ pos_bias,
    const float* __restrict__ R_w, const float* __restrict__ R_b,
    float* __restrict__ out, float* __restrict__ att,
    float* __restrict__ ws, int nbat)
{
    const int t = threadIdx.x;
    const int p = blockIdx.x;
    const int chunk = (nbat * NH) >> 3;
    const int lj = (p & 7) * chunk + (p >> 3);   // XCD-chunk swizzle (bijective)
    const int b = lj >> 3;
    const int h = lj & 7;
    const int lane = t & 63, wave = t >> 6;
    const int l15 = lane & 15, g = lane >> 4;

    __shared__ __align__(16) unsigned char smem[39872];
    unsigned short* sVT = reinterpret_cast<unsigned short*>(smem);
    unsigned short* sK  = reinterpret_cast<unsigned short*>(smem + 14848);
    unsigned short* sQ  = reinterpret_cast<unsigned short*>(smem + 30848);
    unsigned short* sP  = reinterpret_cast<unsigned short*>(smem + 14848);
    float* spb = reinterpret_cast<float*>(smem + 38048);
    float* sM  = reinterpret_cast<float*>(smem + 38848);
    float* sSm = reinterpret_cast<float*>(smem + 39360);

    // ---- P0: zero sVT K-pad (k=200..227 for 32 cols), stage pos_bias ----
    if (t < 448) {
        unsigned int* v32 = reinterpret_cast<unsigned int*>(sVT);
        const int col = t / 14, i = t - col * 14;
        v32[col * 116 + 100 + i] = 0u;
    }
    if (t < NC) spb[t] = pos_bias[t];

    // ---- P1: projections, W-hoisted strips (split-bf16, 3-term) ----
    {
        const int s0 = (wave * 60) >> 3;
        const int s1 = ((wave + 1) * 60) >> 3;
        int cp = -1, cn = -1;
        bh8 wh[4], wl[4];
        float bias = 0.f;
        for (int id = s0; id < s1; ++id) {
            int pidx, nt, mt2;
            if (id < 8)       { pidx = 0; nt = id >> 2; mt2 = id & 3; }
            else if (id < 34) { int j = id - 8;  pidx = 1; nt = j / 13; mt2 = j - nt * 13; }
            else              { int j = id - 34; pidx = 2; nt = j / 13; mt2 = j - nt * 13; }
            const int col = (nt << 4) + l15;
            if (pidx != cp || nt != cn) {
                cp = pidx; cn = nt;
                const float* Wm = (pidx == 0) ? At_w : (pidx == 1) ? Ac_w : Bc_w;
                const float* Wb = (pidx == 0) ? At_b : (pidx == 1) ? Ac_b : Bc_b;
                const float* bp = Wm + (size_t)(h * DH + col) * EMB + (g << 3);
                #pragma unroll
                for (int ks = 0; ks < 4; ++ks) split8(bp + ks * 32, wh[ks], wl[ks]);
                bias = Wb[h * DH + col];
            }
            const int nrows = (pidx == 0) ? NT : NC;
            const float* Xb = (pidx == 0) ? gq : (pidx == 1) ? gk : gv;
            int ar = mt2 * 16 + l15; if (ar > nrows - 1) ar = nrows - 1;
            const float* ap = Xb + (size_t)b * nrows * EMB + (size_t)ar * EMB + (g << 3);
            f4acc acc2 = {bias, bias, bias, bias};
            #pragma unroll
            for (int ks = 0; ks < 4; ++ks) {
                bh8 xh, xl;
                split8(ap + ks * 32, xh, xl);
                acc2 = mfma_bf16(xh, wh[ks], acc2);
                acc2 = mfma_bf16(xl, wh[ks], acc2);
                acc2 = mfma_bf16(xh, wl[ks], acc2);
            }
            #pragma unroll
            for (int r = 0; r < 4; ++r) {
                const int row = mt2 * 16 + (g << 2) + r;
                if (row < nrows) {
                    const unsigned short hv = bf16rne(acc2[r]);
                    if (pidx == 0)      sQ[row * 40 + col] = hv;
                    else if (pidx == 1) sK[row * 40 + col] = hv;
                    else                sVT[col * 232 + row] = hv;
                }
            }
        }
    }
    __syncthreads();

    // ---- P3: scores in registers; norms in-register from the fragments ----
    const int mt = wave & 3, hf = wave >> 2;
    const int m0 = mt << 4;
    const int row64 = m0 + (g << 2);
    int arow = m0 + l15; if (arow > NT - 1) arow = NT - 1;
    const bh8 aq = *reinterpret_cast<const bh8*>(sQ + arow * 40 + (g << 3));

    // qn: A-frag row m0+l15 lives on the 4 lanes {l15, l15+16, +32, +48}
    float qn2 = 0.f;
    #pragma unroll
    for (int e = 0; e < 8; ++e) {
        const float v = __uint_as_float(((unsigned int)(unsigned short)aq[e]) << 16);
        qn2 += v * v;
    }
    qn2 += __shfl_xor(qn2, 16);
    qn2 += __shfl_xor(qn2, 32);
    float qn_r[4];                       // move qn to this lane's 4 C-rows
    #pragma unroll
    for (int r = 0; r < 4; ++r) qn_r[r] = sqrtf(__shfl(qn2, (g << 2) + r, 64));

    f4acc acc[7];
    #pragma unroll
    for (int i = 0; i < 7; ++i) {
        const int nt = hf * 7 + i;
        if (nt < 13) {
            const int col = (nt << 4) + l15;
            const int bc = (col < NC) ? col : (NC - 1);
            const bh8 bk = *reinterpret_cast<const bh8*>(sK + bc * 40 + (g << 3));
            float kn2 = 0.f;
            #pragma unroll
            for (int e = 0; e < 8; ++e) {
                const float v = __uint_as_float(((unsigned int)(unsigned short)bk[e]) << 16);
                kn2 += v * v;
            }
            kn2 += __shfl_xor(kn2, 16);  // kn lands on C-col lanes directly
            kn2 += __shfl_xor(kn2, 32);
            const float kn = sqrtf(kn2);
            f4acc c = {0.f, 0.f, 0.f, 0.f};
            c = mfma_bf16(aq, bk, c);
            const float pb = spb[bc];
            #pragma unroll
            for (int r = 0; r < 4; ++r)
                acc[i][r] = (col < NC) ? c[r] / fmaxf(qn_r[r] * kn, 1e-6f) + pb
                                       : -1e30f;
        }
    }
    __syncthreads();                 // sK/sQ dead; sP region live from here

    // ---- P4a: sP K-pad zero (ALL 50 rows; grid-stride) + per-half row max ----
    {
        unsigned int* p32 = reinterpret_cast<unsigned int*>(sP);
        for (int tt = t; tt < 700; tt += THREADS) {
            const int row = tt / 14, i = tt - row * 14;
            p32[row * 116 + 100 + i] = 0u;
        }
    }
    {
        float mloc[4] = {-1e30f, -1e30f, -1e30f, -1e30f};
        #pragma unroll
        for (int i = 0; i < 7; ++i) {
            if (hf * 7 + i < 13) {
                #pragma unroll
                for (int r = 0; r < 4; ++r) mloc[r] = fmaxf(mloc[r], acc[i][r]);
            }
        }
        #pragma unroll
        for (int r = 0; r < 4; ++r) {
            mloc[r] = fmaxf(mloc[r], __shfl_xor(mloc[r], 1));
            mloc[r] = fmaxf(mloc[r], __shfl_xor(mloc[r], 2));
            mloc[r] = fmaxf(mloc[r], __shfl_xor(mloc[r], 4));
            mloc[r] = fmaxf(mloc[r], __shfl_xor(mloc[r], 8));
        }
        if (l15 == 0) {
            #pragma unroll
            for (int r = 0; r < 4; ++r) sM[hf * 64 + row64 + r] = mloc[r];
        }
    }
    __syncthreads();

    // ---- P4b: global max, exp, per-half sums ----
    {
        float mx[4], sl[4] = {0.f, 0.f, 0.f, 0.f};
        #pragma unroll
        for (int r = 0; r < 4; ++r)
            mx[r] = fmaxf(sM[row64 + r], sM[64 + row64 + r]);
        #pragma unroll
        for (int i = 0; i < 7; ++i) {
            if (hf * 7 + i < 13) {
                #pragma unroll
                for (int r = 0; r < 4; ++r) {
                    float e = __expf(acc[i][r] - mx[r]);
                    acc[i][r] = e;
                    sl[r] += e;
                }
            }
        }
        #pragma unroll
        for (int r = 0; r < 4; ++r) {
            sl[r] += __shfl_xor(sl[r], 1);
            sl[r] += __shfl_xor(sl[r], 2);
            sl[r] += __shfl_xor(sl[r], 4);
            sl[r] += __shfl_xor(sl[r], 8);
        }
        if (l15 == 0) {
            #pragma unroll
            for (int r = 0; r < 4; ++r) sSm[hf * 64 + row64 + r] = sl[r];
        }
    }
    __syncthreads();

    // ---- P4c: normalize, write att (f32 global) + P (bf16 LDS) ----
    {
        float inv[4];
        #pragma unroll
        for (int r = 0; r < 4; ++r)
            inv[r] = 1.0f / (sSm[row64 + r] + sSm[64 + row64 + r]);
        float* attb = att + (size_t)(b * NH + h) * NT * NC;
        #pragma unroll
        for (int i = 0; i < 7; ++i) {
            const int nt = hf * 7 + i;
            if (nt < 13) {
                const int col = (nt << 4) + l15;
                if (col < NC) {
                    #pragma unroll
                    for (int r = 0; r < 4; ++r) {
                        const int row = row64 + r;
                        if (row < NT) {
                            const float v = acc[i][r] * inv[r];
                            attb[row * NC + col] = v;
                            sP[row * 232 + col] = bf16rne(v);
                        }
                    }
                }
            }
        }
    }
    __syncthreads();

    // ---- P5: PV (bf16 MFMA, K=224 zero-padded) ----
    {
        const int pnt = wave >> 2;               // 2 col-tiles of 16 (DH=32)
        const unsigned short* pA = sP + arow * 232;
        const unsigned short* pB = sVT + (size_t)((pnt << 4) + l15) * 232;
        f4acc o = {0.f, 0.f, 0.f, 0.f};
        #pragma unroll
        for (int ks = 0; ks < 7; ++ks) {
            const bh8 a = *reinterpret_cast<const bh8*>(pA + ks * 32 + (g << 3));
            const bh8 v = *reinterpret_cast<const bh8*>(pB + ks * 32 + (g << 3));
            o = mfma_bf16(a, v, o);
        }
        if (WSP) {
            // ws layout = cat rows: [b][row][h*32 + c]
            float* wsb = ws + (size_t)b * (NT * NH * DH) + h * DH;
            #pragma unroll
            for (int r = 0; r < 4; ++r) {
                const int row = row64 + r;
                if (row < NT) wsb[(size_t)row * (NH * DH) + (pnt << 4) + l15] = o[r];
            }
        } else {
            __syncthreads();
            float* sOH = reinterpret_cast<float*>(smem);   // 6400 B over sVT
            #pragma unroll
            for (int r = 0; r < 4; ++r) {
                const int row = row64 + r;
                if (row < NT) sOH[row * DH + (pnt << 4) + l15] = o[r];
            }
            __syncthreads();
            for (int oo = t; oo < NT * EMB; oo += THREADS) {
                const int r = oo >> 7, e = oo & 127;
                float s = (h == 0) ? R_b[e] : 0.f;
                const float* rw = R_w + (size_t)e * (NH * DH) + h * DH;
                const float* oh = sOH + r * DH;
                #pragma unroll
                for (int c = 0; c < DH; ++c) s += oh[c] * rw[c];
                atomicAdd(&out[((size_t)b * NT + r) * EMB + e], s);
            }
        }
    }
}

// rproj4: MFMA GEMM. out[51200x128] = cat[51200x256] @ R_w[128x256]^T + R_b.
// Grid 800 blocks x 256 thr (4 waves); wave owns a 16-row M-tile x all 8
// N-tiles; K=256 in 8 steps; 3-term split-bf16 (f32 quality).
__global__ __launch_bounds__(256, 4) void rproj4(
    const float* __restrict__ ws, const float* __restrict__ R_w,
    const float* __restrict__ R_b, float* __restrict__ out)
{
    const int t = threadIdx.x;
    const int lane = t & 63, wave = t >> 6;
    const int l15 = lane & 15, g = lane >> 4;
    const int m0 = blockIdx.x * 64 + wave * 16;
    const float* ap = ws + (size_t)(m0 + l15) * 256 + (g << 3);

    f4acc acc[8];
    #pragma unroll
    for (int nt = 0; nt < 8; ++nt) {
        const float rb = R_b[nt * 16 + l15];
        acc[nt][0] = rb; acc[nt][1] = rb; acc[nt][2] = rb; acc[nt][3] = rb;
    }
    #pragma unroll
    for (int ks = 0; ks < 8; ++ks) {
        bh8 ah, al;
        split8(ap + ks * 32, ah, al);
        #pragma unroll
        for (int nt = 0; nt < 8; ++nt) {
            bh8 bh_, bl_;
            split8(R_w + (size_t)(nt * 16 + l15) * 256 + ks * 32 + (g << 3), bh_, bl_);
            acc[nt] = mfma_bf16(ah, bh_, acc[nt]);
            acc[nt] = mfma_bf16(al, bh_, acc[nt]);
            acc[nt] = mfma_bf16(ah, bl_, acc[nt]);
        }
    }
    const int row = m0 + (g << 2);
    #pragma unroll
    for (int nt = 0; nt < 8; ++nt) {
        #pragma unroll
        for (int r = 0; r < 4; ++r)
            out[(size_t)(row + r) * EMB + nt * 16 + l15] = acc[nt][r];
    }
}

extern "C" void kernel_launch(void* const* d_in, const int* in_sizes, int n_in,
                              void* d_out, int out_size, void* d_ws, size_t ws_size,
                              hipStream_t stream)
{
    const float* gq   = (const float*)d_in[0];
    const float* gk   = (const float*)d_in[1];
    const float* gv   = (const float*)d_in[2];
    const float* At_w = (const float*)d_in[3];
    const float* At_b = (const float*)d_in[4];
    const float* Ac_w = (const float*)d_in[5];
    const float* Ac_b = (const float*)d_in[6];
    const float* Bc_w = (const float*)d_in[7];
    const float* Bc_b = (const float*)d_in[8];
    const float* pb   = (const float*)d_in[9];
    const float* R_w  = (const float*)d_in[10];
    const float* R_b  = (const float*)d_in[11];

    const int nbat = in_sizes[0] / (NT * EMB);   // 1024
    float* out = (float*)d_out;
    float* att = out + (size_t)nbat * NT * EMB;

    const size_t ws_need = (size_t)nbat * NT * NH * DH * sizeof(float);
    const int nwg = nbat * NH;

    if (ws_size >= ws_need) {
        attn_mfma<1><<<nwg, THREADS, 0, stream>>>(
            gq, gk, gv, At_w, At_b, Ac_w, Ac_b, Bc_w, Bc_b, pb, R_w, R_b,
            out, att, (float*)d_ws, nbat);
        rproj4<<<(nbat * NT) / 64, 256, 0, stream>>>((float*)d_ws, R_w, R_b, out);
    } else {
        hipMemsetAsync(d_out, 0, (size_t)nbat * NT * EMB * sizeof(float), stream);
        attn_mfma<0><<<nwg, THREADS, 0, stream>>>(
            gq, gk, gv, At_w, At_b, Ac_w, Ac_b, Bc_w, Bc_b, pb, R_w, R_b,
            out, att, nullptr, nbat);
    }
}